// Round 8
// baseline (880.035 us; speedup 1.0000x reference)
//
#include <hip/hip_runtime.h>
#include <hip/hip_bf16.h>

#define N_NODES 50000
#define N_EDGES 800000
#define IN_CH   256
#define EDGE_DIM 32
#define NH 4
#define NC 32
#define HC 128   // NH*NC
#define SCAN_BLKS 196   // 196 * 256 = 50176 >= N_NODES
#define NTILES (N_NODES / 16)    // 3125 16-node tiles (exact)

typedef __attribute__((ext_vector_type(8))) short bf16x8;
typedef __attribute__((ext_vector_type(4))) float f32x4;

// scan inter-block partials + pre-split transposed weights: device globals
__device__ int g_bsum[256];
__device__ int g_boffs[256];
// W concat [Wsrc | Wdst] transposed: index [c*256 + k], c in [0,256), k in [0,256)
__device__ __align__(16) unsigned short g_wt_hi[256 * 256];
__device__ __align__(16) unsigned short g_wt_lo[256 * 256];

// hw transcendentals (avoid __exp2f/__log2f: glibc math.h name collision)
__device__ __forceinline__ float fexp2(float x) { return __builtin_amdgcn_exp2f(x); }
__device__ __forceinline__ float flog2(float x) { return __builtin_amdgcn_logf(x); }
__device__ __forceinline__ float fexp(float x)  { return __builtin_amdgcn_exp2f(x * 1.44269504089f); }

// fast tanh: 1 - 2/(e^{2x}+1); exact saturation at +/-inf, ~1e-7 abs err
__device__ __forceinline__ float ftanh(float x) {
    const float e = fexp2(x * 2.88539008178f);   // 2*log2(e)
    return 1.0f - 2.0f * __builtin_amdgcn_rcpf(e + 1.0f);
}

// f32 -> bf16 RNE
__device__ __forceinline__ unsigned short f2bf(float f) {
    union { float f; unsigned int u; } v; v.f = f;
    const unsigned int r = v.u + 0x7fffu + ((v.u >> 16) & 1u);
    return (unsigned short)(r >> 16);
}

// split f32x8 into truncated-bf16 hi + bf16 lo (x ~= hi + lo, err ~2^-17)
__device__ __forceinline__ void split8(const float4 a, const float4 b, bf16x8& hi, bf16x8& lo) {
    union { unsigned short us[8]; bf16x8 v; } H, L;
    const float xs[8] = {a.x, a.y, a.z, a.w, b.x, b.y, b.z, b.w};
    #pragma unroll
    for (int e = 0; e < 8; ++e) {
        const unsigned int u = __float_as_uint(xs[e]);
        H.us[e] = (unsigned short)(u >> 16);
        const float lof = xs[e] - __uint_as_float(u & 0xffff0000u);  // exact
        L.us[e] = (unsigned short)(__float_as_uint(lof) >> 16);
    }
    hi = H.v; lo = L.v;
}

// Dual-dtype scalar load: f32 flag selects fp32 vs bf16 interpretation of the raw buffer.
__device__ __forceinline__ float ldf(const void* p, long i, bool f32) {
    return f32 ? ((const float*)p)[i]
               : __bfloat162float(((const __hip_bfloat16*)p)[i]);
}

// Dual-width index loads: idx64 => buffer is int64 [2,E] (values < 2^31, read low words).
__device__ __forceinline__ int ld_src(const int* ei, long e, bool idx64) {
    return idx64 ? ei[2 * e] : ei[e];
}
__device__ __forceinline__ int ld_dst(const int* ei, long e, bool idx64) {
    return idx64 ? ei[2 * ((long)N_EDGES + e)] : ei[(long)N_EDGES + e];
}

// ---------------- dtype detection (runs every call, deterministic) ----------------
__global__ __launch_bounds__(256) void detect_k(const unsigned short* __restrict__ xu,
                                                const int* __restrict__ ei,
                                                int* __restrict__ flag) {
    __shared__ int zc, bc, nz_idx;
    if (threadIdx.x == 0) { zc = 0; bc = 0; nz_idx = 0; }
    __syncthreads();
    int z = 0, b = 0, hi = 0;
    for (int i = threadIdx.x; i < 4096; i += 256) {
        const unsigned short w = xu[2 * i];
        if (w == 0) ++z;
        if ((w & 0x7F80) == 0x7F80) ++b;
    }
    for (int i = threadIdx.x; i < 2048; i += 256)
        if (ei[2 * i + 1] != 0) hi = 1;
    atomicAdd(&zc, z);
    atomicAdd(&bc, b);
    if (hi) atomicAdd(&nz_idx, 1);
    __syncthreads();
    if (threadIdx.x == 0) {
        flag[0] = (zc > 2048 || bc > 0) ? 1 : 0;  // 1 => fp32 float buffers
        flag[1] = (nz_idx == 0) ? 1 : 0;          // 1 => int64 indices
    }
}

// ---------------- CSR build ----------------
__global__ __launch_bounds__(256) void zero_deg_k(int* __restrict__ deg) {
    const int i = blockIdx.x * 256 + threadIdx.x;
    if (i < N_NODES) deg[i] = 0;
}

__global__ __launch_bounds__(256) void hist_k(const int* __restrict__ ei,
                                              const int* __restrict__ flag,
                                              int* __restrict__ deg) {
    const bool idx64 = (flag[1] != 0);
    const long e = (long)blockIdx.x * 256 + threadIdx.x;
    if (e < N_EDGES) atomicAdd(&deg[ld_dst(ei, e, idx64)], 1);
}

// ---- 3-phase parallel exclusive scan ----
__global__ __launch_bounds__(256) void scan1_k(const int* __restrict__ deg,
                                               int* __restrict__ row_ptr) {
    __shared__ int wsum[4];
    const int tid = threadIdx.x;
    const int lane = tid & 63, wid = tid >> 6;
    const int i = blockIdx.x * 256 + tid;
    const int v = (i < N_NODES) ? deg[i] : 0;
    int x = v;
    #pragma unroll
    for (int off = 1; off < 64; off <<= 1) {
        const int t = __shfl_up(x, off);
        if (lane >= off) x += t;
    }
    if (lane == 63) wsum[wid] = x;
    __syncthreads();
    int wpre = 0;
    for (int w = 0; w < wid; ++w) wpre += wsum[w];
    if (i < N_NODES) row_ptr[i] = wpre + x - v;          // block-local exclusive
    if (tid == 0) g_bsum[blockIdx.x] = wsum[0] + wsum[1] + wsum[2] + wsum[3];
}

__global__ __launch_bounds__(256) void scan2_k(int* __restrict__ row_ptr) {
    __shared__ int wsum[4];
    const int tid = threadIdx.x;
    const int lane = tid & 63, wid = tid >> 6;
    const int v = (tid < SCAN_BLKS) ? g_bsum[tid] : 0;
    int x = v;
    #pragma unroll
    for (int off = 1; off < 64; off <<= 1) {
        const int t = __shfl_up(x, off);
        if (lane >= off) x += t;
    }
    if (lane == 63) wsum[wid] = x;
    __syncthreads();
    int wpre = 0;
    for (int w = 0; w < wid; ++w) wpre += wsum[w];
    if (tid < SCAN_BLKS) g_boffs[tid] = wpre + x - v;
    if (tid == 0) row_ptr[N_NODES] = N_EDGES;            // total degree is constant
}

__global__ __launch_bounds__(256) void scan3_k(int* __restrict__ row_ptr,
                                               int* __restrict__ cursor) {
    const int i = blockIdx.x * 256 + threadIdx.x;
    if (i < N_NODES) {
        const int t = row_ptr[i] + g_boffs[blockIdx.x];
        row_ptr[i] = t;
        cursor[i] = t;
    }
}

// packed CSR payload: one 8B store per edge (halves random-store RMW traffic)
__global__ __launch_bounds__(256) void scatter_k(const int* __restrict__ ei,
                                                 const int* __restrict__ flag,
                                                 int* __restrict__ cursor,
                                                 int2* __restrict__ epack) {
    const bool idx64 = (flag[1] != 0);
    const long e = (long)blockIdx.x * 256 + threadIdx.x;
    if (e >= N_EDGES) return;
    const int dst = ld_dst(ei, e, idx64);
    const int src = ld_src(ei, e, idx64);
    const int pos = atomicAdd(&cursor[dst], 1);
    epack[pos] = make_int2((int)e, src);
}

// ---------------- W pre-split (fp32 path): transpose + hi/lo bf16 split ----------------
__global__ __launch_bounds__(256) void w_split_k(const float* __restrict__ Wsrc,
                                                 const float* __restrict__ Wdst,
                                                 const int* __restrict__ flag) {
    if (flag[0] == 0) return;        // bf16 inputs: not needed
    const int i = blockIdx.x * 256 + threadIdx.x;   // 65536 elems, one per thread
    const int c = i >> 8;
    const int k = i & 255;
    const float w = (c < HC) ? Wsrc[k * HC + c] : Wdst[k * HC + (c - HC)];
    const unsigned int u = __float_as_uint(w);
    g_wt_hi[i] = (unsigned short)(u >> 16);
    const float lof = w - __uint_as_float(u & 0xffff0000u);
    g_wt_lo[i] = (unsigned short)(__float_as_uint(lof) >> 16);
}

// ---------------- node GEMM (fp32 inputs): split-bf16 MFMA, fp32-accurate ----------------
__global__ __launch_bounds__(512) void node_gemm_f32s_k(const float* __restrict__ x,
                                                        const int* __restrict__ flag,
                                                        float* __restrict__ xsrc,
                                                        float* __restrict__ xdst) {
    if (flag[0] == 0) return;        // bf16 inputs: node_gemm_mfma_k handles it
    const int tid = threadIdx.x;
    const int l   = tid & 63;
    const int wv  = tid >> 6;        // wave 0..7
    const int jj  = l & 15;
    const int hi4 = l >> 4;
    const int cbase = wv * 32;

    bf16x8 bhi[8][2], blo[8][2];
    #pragma unroll
    for (int ks = 0; ks < 8; ++ks)
        #pragma unroll
        for (int t = 0; t < 2; ++t) {
            const int off = (cbase + t * 16 + jj) * 256 + ks * 32 + hi4 * 8;
            bhi[ks][t] = *(const bf16x8*)(g_wt_hi + off);
            blo[ks][t] = *(const bf16x8*)(g_wt_lo + off);
        }

    for (int nt = blockIdx.x; nt < NTILES; nt += gridDim.x) {
        const long n0 = (long)nt * 16;
        const float* xr = x + (n0 + jj) * IN_CH;

        f32x4 acc[2];
        acc[0] = (f32x4){0.f, 0.f, 0.f, 0.f};
        acc[1] = (f32x4){0.f, 0.f, 0.f, 0.f};
        #pragma unroll
        for (int ks = 0; ks < 8; ++ks) {
            const float4 a0 = *(const float4*)(xr + ks * 32 + hi4 * 8);
            const float4 a1 = *(const float4*)(xr + ks * 32 + hi4 * 8 + 4);
            bf16x8 ahi, alo;
            split8(a0, a1, ahi, alo);
            #pragma unroll
            for (int t = 0; t < 2; ++t) {
                acc[t] = __builtin_amdgcn_mfma_f32_16x16x32_bf16(ahi, bhi[ks][t], acc[t], 0, 0, 0);
                acc[t] = __builtin_amdgcn_mfma_f32_16x16x32_bf16(ahi, blo[ks][t], acc[t], 0, 0, 0);
                acc[t] = __builtin_amdgcn_mfma_f32_16x16x32_bf16(alo, bhi[ks][t], acc[t], 0, 0, 0);
            }
        }

        #pragma unroll
        for (int t = 0; t < 2; ++t) {
            const int c = cbase + t * 16 + jj;
            float* obase = (c < HC) ? (xsrc + c) : (xdst + (c - HC));
            #pragma unroll
            for (int r = 0; r < 4; ++r)
                obase[(n0 + hi4 * 4 + r) * HC] = acc[t][r];
        }
    }
}

// ---------------- node GEMM (bf16 inputs): MFMA ----------------
__global__ __launch_bounds__(256) void node_gemm_mfma_k(const unsigned short* __restrict__ x,
                                                        const unsigned short* __restrict__ Wsrc,
                                                        const unsigned short* __restrict__ Wdst,
                                                        const int* __restrict__ flag,
                                                        float* __restrict__ xsrc,
                                                        float* __restrict__ xdst) {
    if (flag[0] != 0) return;        // fp32 inputs: node_gemm_f32s_k handles it
    const int tid = threadIdx.x;
    const int l   = tid & 63;
    const int w   = tid >> 6;
    const int jj  = l & 15;
    const int hi  = l >> 4;
    const int cbase = w * 64;

    bf16x8 bfrag[8][4];
    #pragma unroll
    for (int ks = 0; ks < 8; ++ks)
        #pragma unroll
        for (int t = 0; t < 4; ++t) {
            const int c = cbase + t * 16 + jj;
            const unsigned short* Wp = (c < HC) ? (Wsrc + c) : (Wdst + (c - HC));
            union { unsigned short u[8]; bf16x8 v; } bu;
            #pragma unroll
            for (int i = 0; i < 8; ++i)
                bu.u[i] = Wp[(ks * 32 + hi * 8 + i) * HC];
            bfrag[ks][t] = bu.v;
        }

    for (int nt = blockIdx.x; nt < NTILES; nt += gridDim.x) {
        const long n0 = (long)nt * 16;
        const unsigned short* xr = x + (n0 + jj) * IN_CH + hi * 8;
        bf16x8 afrag[8];
        #pragma unroll
        for (int ks = 0; ks < 8; ++ks)
            afrag[ks] = *(const bf16x8*)(xr + ks * 32);

        f32x4 acc[4];
        #pragma unroll
        for (int t = 0; t < 4; ++t) acc[t] = (f32x4){0.f, 0.f, 0.f, 0.f};
        #pragma unroll
        for (int ks = 0; ks < 8; ++ks)
            #pragma unroll
            for (int t = 0; t < 4; ++t)
                acc[t] = __builtin_amdgcn_mfma_f32_16x16x32_bf16(afrag[ks], bfrag[ks][t], acc[t], 0, 0, 0);

        #pragma unroll
        for (int t = 0; t < 4; ++t) {
            const int c = cbase + t * 16 + jj;
            float* obase = (c < HC) ? (xsrc + c) : (xdst + (c - HC));
            #pragma unroll
            for (int r = 0; r < 4; ++r)
                obase[(n0 + hi * 4 + r) * HC] = acc[t][r];
        }
    }
}

// ---------------- FUSED edge-alpha + aggregation: one wave per dst node ----------------
// grid = N/4 blocks, 4 waves each -> exactly one node per wave (TLP hides gather
// latency; R7's grid=2048 serialized 6 nodes/wave and was latency-bound).
__global__ __launch_bounds__(256) void fused_edge_agg_k(const int* __restrict__ row_ptr,
                                                        const int2* __restrict__ epack,
                                                        const void* __restrict__ eattr,
                                                        const void* __restrict__ dw,
                                                        const void* __restrict__ Wedge,
                                                        const void* __restrict__ att,
                                                        const void* __restrict__ sscale,
                                                        const int* __restrict__ flag,
                                                        const float* __restrict__ xsrc,
                                                        const float* __restrict__ xdst,
                                                        float* __restrict__ ea_ws,
                                                        float* __restrict__ araw_out,
                                                        float* __restrict__ s_ws,
                                                        float* __restrict__ out) {
    const bool f32 = (flag[0] != 0);
    __shared__ int   sEid[4][16];
    __shared__ int   sSrc[4][16];
    __shared__ float sDw[4][16];

    const int tid = threadIdx.x;
    const int l   = tid & 63;
    const int wid = tid >> 6;
    const int jj  = l & 15;     // col-within-tile / A-edge index
    const int hi  = l >> 4;     // lane quarter-group

    // B fragments: W_edge[32][128], loaded once per block
    bf16x8 bfrag[8];
    #pragma unroll
    for (int t = 0; t < 8; ++t) {
        union { unsigned short u[8]; bf16x8 v; } bu;
        #pragma unroll
        for (int i = 0; i < 8; ++i) {
            const int k = hi * 8 + i;
            const int col = t * 16 + jj;
            if (f32) bu.u[i] = f2bf(((const float*)Wedge)[k * HC + col]);
            else     bu.u[i] = ((const unsigned short*)Wedge)[k * HC + col];
        }
        bfrag[t] = bu.v;
    }
    float attv[8];
    #pragma unroll
    for (int t = 0; t < 8; ++t) attv[t] = ldf(att, t * 16 + jj, f32);
    float ss4[4];
    #pragma unroll
    for (int h2 = 0; h2 < 4; ++h2) ss4[h2] = ldf(sscale, h2, f32);

    const int n = blockIdx.x * 4 + wid;     // one node per wave (N divisible by 4)
    const int p0 = row_ptr[n];
    const int p1 = row_ptr[n + 1];

    float xdv[8];
    #pragma unroll
    for (int t = 0; t < 8; ++t) xdv[t] = xdst[(long)n * HC + jj + t * 16];

    float ax[8] = {0,0,0,0,0,0,0,0};
    float sal[4] = {0,0,0,0};

    for (int base = p0; base < p1; base += 16) {
        if (l < 16) {
            const int2 pk = epack[min(base + l, p1 - 1)];
            sEid[wid][l] = pk.x;
            sSrc[wid][l] = pk.y;
            sDw[wid][l]  = ldf(dw, pk.x, f32);
        }
        __builtin_amdgcn_wave_barrier();

        // A fragment: eattr row of edge sEid[jj], k-chunk hi*8..hi*8+8
        const long eA = sEid[wid][jj];
        bf16x8 afrag;
        if (f32) {
            const float* ar = (const float*)eattr + eA * EDGE_DIM + hi * 8;
            const float4 q0 = *(const float4*)ar;
            const float4 q1 = *(const float4*)(ar + 4);
            union { unsigned short u[8]; bf16x8 v; } au;
            au.u[0] = f2bf(q0.x); au.u[1] = f2bf(q0.y); au.u[2] = f2bf(q0.z); au.u[3] = f2bf(q0.w);
            au.u[4] = f2bf(q1.x); au.u[5] = f2bf(q1.y); au.u[6] = f2bf(q1.z); au.u[7] = f2bf(q1.w);
            afrag = au.v;
        } else {
            afrag = *(const bf16x8*)((const unsigned short*)eattr + eA * EDGE_DIM + hi * 8);
        }

        const f32x4 zero = {0.f, 0.f, 0.f, 0.f};
        f32x4 acc[8];
        #pragma unroll
        for (int t = 0; t < 8; ++t)
            acc[t] = __builtin_amdgcn_mfma_f32_16x16x32_bf16(afrag, bfrag[t], zero, 0, 0, 0);

        // gather xsrc rows (kept for aggregation), tanh + att partial sums
        float xsv[4][8];
        float hsum[4][4] = {{0,0,0,0},{0,0,0,0},{0,0,0,0},{0,0,0,0}};
        #pragma unroll
        for (int r = 0; r < 4; ++r) {
            const int sI = sSrc[wid][hi * 4 + r];
            const float* bs = xsrc + (long)sI * HC + jj;
            #pragma unroll
            for (int t = 0; t < 8; ++t) xsv[r][t] = bs[t * 16];
            #pragma unroll
            for (int t = 0; t < 8; ++t) {
                const float v = ftanh(acc[t][r] + xsv[r][t] + xdv[t]) * attv[t];
                hsum[r][t >> 1] += v;
            }
        }

        // reduce over the 16 lanes of the group (all lanes end with full sums)
        #pragma unroll
        for (int r = 0; r < 4; ++r)
            #pragma unroll
            for (int h2 = 0; h2 < 4; ++h2) {
                float v = hsum[r][h2];
                v += __shfl_xor(v, 1);
                v += __shfl_xor(v, 2);
                v += __shfl_xor(v, 4);
                v += __shfl_xor(v, 8);
                hsum[r][h2] = v;
            }

        // ea for all (r, head), masked by tile validity
        float eaV[4][4];
        #pragma unroll
        for (int r = 0; r < 4; ++r) {
            const bool valid = (base + hi * 4 + r) < p1;
            const float lg = flog2(sDw[wid][hi * 4 + r]);
            #pragma unroll
            for (int h2 = 0; h2 < 4; ++h2) {
                const float d = fexp2(ss4[h2] * lg);
                eaV[r][h2] = valid ? fexp(hsum[r][h2] * d) : 0.0f;
            }
        }

        // scattered per-edge stores: lane jj <-> (r_sel = jj>>2, head = jj&3)
        {
            const int r_sel = jj >> 2, hh = jj & 3;
            if (base + hi * 4 + r_sel < p1) {
                float pval = hsum[0][0], eval = eaV[0][0];
                #pragma unroll
                for (int r = 0; r < 4; ++r)
                    #pragma unroll
                    for (int h2 = 0; h2 < 4; ++h2)
                        if (jj == r * 4 + h2) { pval = hsum[r][h2]; eval = eaV[r][h2]; }
                const long e2 = sEid[wid][hi * 4 + r_sel];
                araw_out[e2 * 4 + hh] = pval;
                ea_ws[e2 * 4 + hh]    = eval;
            }
        }

        // aggregation: ax[c] += ea * xs[c]; sal[h] += ea (group-local 4 edges)
        #pragma unroll
        for (int r = 0; r < 4; ++r) {
            #pragma unroll
            for (int t = 0; t < 8; ++t)
                ax[t] += eaV[r][t >> 1] * xsv[r][t];
            #pragma unroll
            for (int h2 = 0; h2 < 4; ++h2) sal[h2] += eaV[r][h2];
        }
        __builtin_amdgcn_wave_barrier();
    }

    // combine the 4 lane-groups (lane bits 4,5)
    #pragma unroll
    for (int t = 0; t < 8; ++t) {
        ax[t] += __shfl_xor(ax[t], 16);
        ax[t] += __shfl_xor(ax[t], 32);
    }
    #pragma unroll
    for (int h2 = 0; h2 < 4; ++h2) {
        sal[h2] += __shfl_xor(sal[h2], 16);
        sal[h2] += __shfl_xor(sal[h2], 32);
    }
    float inv[4];
    #pragma unroll
    for (int h2 = 0; h2 < 4; ++h2) inv[h2] = 1.0f / (sal[h2] + 1e-8f);

    // out row: lane writes channels jj + 16*(hi*2) and jj + 16*(hi*2+1)
    {
        const int t0 = hi * 2, t1 = t0 + 1;
        out[(long)n * HC + jj + 16 * t0] = ax[t0] * inv[t0 >> 1];
        out[(long)n * HC + jj + 16 * t1] = ax[t1] * inv[t1 >> 1];
    }
    if (l < 4) s_ws[(long)n * 4 + l] = sal[l];
}

// ---------------- edge finalize: alpha_norm = ea / (s[dst] + 1e-8) ----------------
__global__ __launch_bounds__(256) void edge_norm_k(const int* __restrict__ ei,
                                                   const int* __restrict__ flag,
                                                   const float* __restrict__ ea_ws,
                                                   const float* __restrict__ s_ws,
                                                   float* __restrict__ anorm) {
    const bool idx64 = (flag[1] != 0);
    const long i = (long)blockIdx.x * 256 + threadIdx.x;
    if (i >= (long)N_EDGES * NH) return;
    const long e = i >> 2;
    const int h = (int)(i & 3);
    const int dst = ld_dst(ei, e, idx64);
    anorm[i] = ea_ws[i] / (s_ws[(long)dst * 4 + h] + 1e-8f);
}

extern "C" void kernel_launch(void* const* d_in, const int* in_sizes, int n_in,
                              void* d_out, int out_size, void* d_ws, size_t ws_size,
                              hipStream_t stream) {
    const void* x      = d_in[0];
    const int*  ei     = (const int*)d_in[1];
    const void* eattr  = d_in[2];
    const void* dw     = d_in[3];
    const void* Wsrc   = d_in[4];
    const void* Wdst   = d_in[5];
    const void* Wedge  = d_in[6];
    const void* att    = d_in[7];
    const void* sscale = d_in[8];

    float* out   = (float*)d_out;                   // reference output dtype: float32
    float* anorm = out + (long)N_NODES * HC;
    float* araw  = anorm + (long)N_EDGES * NH;

    float* ws      = (float*)d_ws;
    int*   flag    = (int*)d_ws;                    // 64-float pad
    float* xsrc    = ws + 64;                       // N*128
    float* xdst    = xsrc + (long)N_NODES * HC;     // N*128
    float* ea      = xdst + (long)N_NODES * HC;     // E*4
    float* s_ws    = ea + (long)N_EDGES * NH;       // N*4
    int*   deg     = (int*)(s_ws + (long)N_NODES * NH);   // N
    int*   row_ptr = deg + N_NODES;                 // N+1
    int*   cursor  = row_ptr + N_NODES + 1;         // N
    int*   pad0    = cursor + N_NODES;              // 1 int pad -> 8B alignment
    int2*  epack   = (int2*)(pad0 + 1);             // E int2 (same 2E-int footprint)

    detect_k<<<1, 256, 0, stream>>>((const unsigned short*)x, ei, flag);
    zero_deg_k<<<(N_NODES + 255) / 256, 256, 0, stream>>>(deg);
    hist_k<<<(N_EDGES + 255) / 256, 256, 0, stream>>>(ei, flag, deg);
    scan1_k<<<SCAN_BLKS, 256, 0, stream>>>(deg, row_ptr);
    scan2_k<<<1, 256, 0, stream>>>(row_ptr);
    scan3_k<<<SCAN_BLKS, 256, 0, stream>>>(row_ptr, cursor);
    scatter_k<<<(N_EDGES + 255) / 256, 256, 0, stream>>>(ei, flag, cursor, epack);
    w_split_k<<<256, 256, 0, stream>>>((const float*)Wsrc, (const float*)Wdst, flag);
    node_gemm_f32s_k<<<512, 512, 0, stream>>>((const float*)x, flag, xsrc, xdst);
    node_gemm_mfma_k<<<1024, 256, 0, stream>>>((const unsigned short*)x,
                                               (const unsigned short*)Wsrc,
                                               (const unsigned short*)Wdst,
                                               flag, xsrc, xdst);
    fused_edge_agg_k<<<N_NODES / 4, 256, 0, stream>>>(row_ptr, epack, eattr, dw, Wedge,
                                                      att, sscale, flag, xsrc, xdst,
                                                      ea, araw, s_ws, out);
    edge_norm_k<<<((long)N_EDGES * NH + 255) / 256, 256, 0, stream>>>(ei, flag, ea, s_ws, anorm);
}

// Round 10
// 699.464 us; speedup vs baseline: 1.2582x; 1.2582x over previous
//
#include <hip/hip_runtime.h>
#include <hip/hip_bf16.h>

#define N_NODES 50000
#define N_EDGES 800000
#define IN_CH   256
#define EDGE_DIM 32
#define NH 4
#define NC 32
#define HC 128   // NH*NC
#define SCAN_BLKS 196   // 196 * 256 = 50176 >= N_NODES
#define NTILES (N_NODES / 16)    // 3125 16-node tiles (exact)

typedef __attribute__((ext_vector_type(8))) short bf16x8;
typedef __attribute__((ext_vector_type(4))) float f32x4;

// scan inter-block partials + pre-split transposed weights: device globals
__device__ int g_bsum[256];
__device__ int g_boffs[256];
// W concat [Wsrc | Wdst] transposed: index [c*256 + k], c in [0,256), k in [0,256)
__device__ __align__(16) unsigned short g_wt_hi[256 * 256];
__device__ __align__(16) unsigned short g_wt_lo[256 * 256];

// hw transcendentals (avoid __exp2f/__log2f: glibc math.h name collision)
__device__ __forceinline__ float fexp2(float x) { return __builtin_amdgcn_exp2f(x); }
__device__ __forceinline__ float flog2(float x) { return __builtin_amdgcn_logf(x); }
__device__ __forceinline__ float fexp(float x)  { return __builtin_amdgcn_exp2f(x * 1.44269504089f); }

// fast tanh: 1 - 2/(e^{2x}+1); exact saturation at +/-inf, ~1e-7 abs err
__device__ __forceinline__ float ftanh(float x) {
    const float e = fexp2(x * 2.88539008178f);   // 2*log2(e)
    return 1.0f - 2.0f * __builtin_amdgcn_rcpf(e + 1.0f);
}

// f32 -> bf16 RNE
__device__ __forceinline__ unsigned short f2bf(float f) {
    union { float f; unsigned int u; } v; v.f = f;
    const unsigned int r = v.u + 0x7fffu + ((v.u >> 16) & 1u);
    return (unsigned short)(r >> 16);
}

// split f32x8 into truncated-bf16 hi + bf16 lo (x ~= hi + lo, err ~2^-17)
__device__ __forceinline__ void split8(const float4 a, const float4 b, bf16x8& hi, bf16x8& lo) {
    union { unsigned short us[8]; bf16x8 v; } H, L;
    const float xs[8] = {a.x, a.y, a.z, a.w, b.x, b.y, b.z, b.w};
    #pragma unroll
    for (int e = 0; e < 8; ++e) {
        const unsigned int u = __float_as_uint(xs[e]);
        H.us[e] = (unsigned short)(u >> 16);
        const float lof = xs[e] - __uint_as_float(u & 0xffff0000u);  // exact
        L.us[e] = (unsigned short)(__float_as_uint(lof) >> 16);
    }
    hi = H.v; lo = L.v;
}

// Dual-dtype scalar load: f32 flag selects fp32 vs bf16 interpretation of the raw buffer.
__device__ __forceinline__ float ldf(const void* p, long i, bool f32) {
    return f32 ? ((const float*)p)[i]
               : __bfloat162float(((const __hip_bfloat16*)p)[i]);
}

// Dual-width index loads: idx64 => buffer is int64 [2,E] (values < 2^31, read low words).
__device__ __forceinline__ int ld_src(const int* ei, long e, bool idx64) {
    return idx64 ? ei[2 * e] : ei[e];
}
__device__ __forceinline__ int ld_dst(const int* ei, long e, bool idx64) {
    return idx64 ? ei[2 * ((long)N_EDGES + e)] : ei[(long)N_EDGES + e];
}

// ---------------- dtype detection (runs every call, deterministic) ----------------
__global__ __launch_bounds__(256) void detect_k(const unsigned short* __restrict__ xu,
                                                const int* __restrict__ ei,
                                                int* __restrict__ flag) {
    __shared__ int zc, bc, nz_idx;
    if (threadIdx.x == 0) { zc = 0; bc = 0; nz_idx = 0; }
    __syncthreads();
    int z = 0, b = 0, hi = 0;
    for (int i = threadIdx.x; i < 4096; i += 256) {
        const unsigned short w = xu[2 * i];
        if (w == 0) ++z;
        if ((w & 0x7F80) == 0x7F80) ++b;
    }
    for (int i = threadIdx.x; i < 2048; i += 256)
        if (ei[2 * i + 1] != 0) hi = 1;
    atomicAdd(&zc, z);
    atomicAdd(&bc, b);
    if (hi) atomicAdd(&nz_idx, 1);
    __syncthreads();
    if (threadIdx.x == 0) {
        flag[0] = (zc > 2048 || bc > 0) ? 1 : 0;  // 1 => fp32 float buffers
        flag[1] = (nz_idx == 0) ? 1 : 0;          // 1 => int64 indices
    }
}

// ---------------- CSR build ----------------
__global__ __launch_bounds__(256) void zero_deg_k(int* __restrict__ deg) {
    const int i = blockIdx.x * 256 + threadIdx.x;
    if (i < N_NODES) deg[i] = 0;
}

__global__ __launch_bounds__(256) void hist_k(const int* __restrict__ ei,
                                              const int* __restrict__ flag,
                                              int* __restrict__ deg) {
    const bool idx64 = (flag[1] != 0);
    const long e = (long)blockIdx.x * 256 + threadIdx.x;
    if (e < N_EDGES) atomicAdd(&deg[ld_dst(ei, e, idx64)], 1);
}

// ---- 3-phase parallel exclusive scan ----
__global__ __launch_bounds__(256) void scan1_k(const int* __restrict__ deg,
                                               int* __restrict__ row_ptr) {
    __shared__ int wsum[4];
    const int tid = threadIdx.x;
    const int lane = tid & 63, wid = tid >> 6;
    const int i = blockIdx.x * 256 + tid;
    const int v = (i < N_NODES) ? deg[i] : 0;
    int x = v;
    #pragma unroll
    for (int off = 1; off < 64; off <<= 1) {
        const int t = __shfl_up(x, off);
        if (lane >= off) x += t;
    }
    if (lane == 63) wsum[wid] = x;
    __syncthreads();
    int wpre = 0;
    for (int w = 0; w < wid; ++w) wpre += wsum[w];
    if (i < N_NODES) row_ptr[i] = wpre + x - v;          // block-local exclusive
    if (tid == 0) g_bsum[blockIdx.x] = wsum[0] + wsum[1] + wsum[2] + wsum[3];
}

__global__ __launch_bounds__(256) void scan2_k(int* __restrict__ row_ptr) {
    __shared__ int wsum[4];
    const int tid = threadIdx.x;
    const int lane = tid & 63, wid = tid >> 6;
    const int v = (tid < SCAN_BLKS) ? g_bsum[tid] : 0;
    int x = v;
    #pragma unroll
    for (int off = 1; off < 64; off <<= 1) {
        const int t = __shfl_up(x, off);
        if (lane >= off) x += t;
    }
    if (lane == 63) wsum[wid] = x;
    __syncthreads();
    int wpre = 0;
    for (int w = 0; w < wid; ++w) wpre += wsum[w];
    if (tid < SCAN_BLKS) g_boffs[tid] = wpre + x - v;
    if (tid == 0) row_ptr[N_NODES] = N_EDGES;            // total degree is constant
}

__global__ __launch_bounds__(256) void scan3_k(int* __restrict__ row_ptr,
                                               int* __restrict__ cursor) {
    const int i = blockIdx.x * 256 + threadIdx.x;
    if (i < N_NODES) {
        const int t = row_ptr[i] + g_boffs[blockIdx.x];
        row_ptr[i] = t;
        cursor[i] = t;
    }
}

// packed CSR payload: one 8B store per edge
__global__ __launch_bounds__(256) void scatter_k(const int* __restrict__ ei,
                                                 const int* __restrict__ flag,
                                                 int* __restrict__ cursor,
                                                 int2* __restrict__ epack) {
    const bool idx64 = (flag[1] != 0);
    const long e = (long)blockIdx.x * 256 + threadIdx.x;
    if (e >= N_EDGES) return;
    const int dst = ld_dst(ei, e, idx64);
    const int src = ld_src(ei, e, idx64);
    const int pos = atomicAdd(&cursor[dst], 1);
    epack[pos] = make_int2((int)e, src);
}

// ---------------- W pre-split (fp32 path): transpose + hi/lo bf16 split ----------------
__global__ __launch_bounds__(256) void w_split_k(const float* __restrict__ Wsrc,
                                                 const float* __restrict__ Wdst,
                                                 const int* __restrict__ flag) {
    if (flag[0] == 0) return;        // bf16 inputs: not needed
    const int i = blockIdx.x * 256 + threadIdx.x;   // 65536 elems, one per thread
    const int c = i >> 8;
    const int k = i & 255;
    const float w = (c < HC) ? Wsrc[k * HC + c] : Wdst[k * HC + (c - HC)];
    const unsigned int u = __float_as_uint(w);
    g_wt_hi[i] = (unsigned short)(u >> 16);
    const float lof = w - __uint_as_float(u & 0xffff0000u);
    g_wt_lo[i] = (unsigned short)(__float_as_uint(lof) >> 16);
}

// ---------------- node GEMM (fp32 inputs): split-bf16 MFMA, fp32-accurate ----------------
__global__ __launch_bounds__(512) void node_gemm_f32s_k(const float* __restrict__ x,
                                                        const int* __restrict__ flag,
                                                        float* __restrict__ xsrc,
                                                        float* __restrict__ xdst) {
    if (flag[0] == 0) return;        // bf16 inputs: node_gemm_mfma_k handles it
    const int tid = threadIdx.x;
    const int l   = tid & 63;
    const int wv  = tid >> 6;        // wave 0..7
    const int jj  = l & 15;
    const int hi4 = l >> 4;
    const int cbase = wv * 32;

    bf16x8 bhi[8][2], blo[8][2];
    #pragma unroll
    for (int ks = 0; ks < 8; ++ks)
        #pragma unroll
        for (int t = 0; t < 2; ++t) {
            const int off = (cbase + t * 16 + jj) * 256 + ks * 32 + hi4 * 8;
            bhi[ks][t] = *(const bf16x8*)(g_wt_hi + off);
            blo[ks][t] = *(const bf16x8*)(g_wt_lo + off);
        }

    for (int nt = blockIdx.x; nt < NTILES; nt += gridDim.x) {
        const long n0 = (long)nt * 16;
        const float* xr = x + (n0 + jj) * IN_CH;

        f32x4 acc[2];
        acc[0] = (f32x4){0.f, 0.f, 0.f, 0.f};
        acc[1] = (f32x4){0.f, 0.f, 0.f, 0.f};
        #pragma unroll
        for (int ks = 0; ks < 8; ++ks) {
            const float4 a0 = *(const float4*)(xr + ks * 32 + hi4 * 8);
            const float4 a1 = *(const float4*)(xr + ks * 32 + hi4 * 8 + 4);
            bf16x8 ahi, alo;
            split8(a0, a1, ahi, alo);
            #pragma unroll
            for (int t = 0; t < 2; ++t) {
                acc[t] = __builtin_amdgcn_mfma_f32_16x16x32_bf16(ahi, bhi[ks][t], acc[t], 0, 0, 0);
                acc[t] = __builtin_amdgcn_mfma_f32_16x16x32_bf16(ahi, blo[ks][t], acc[t], 0, 0, 0);
                acc[t] = __builtin_amdgcn_mfma_f32_16x16x32_bf16(alo, bhi[ks][t], acc[t], 0, 0, 0);
            }
        }

        #pragma unroll
        for (int t = 0; t < 2; ++t) {
            const int c = cbase + t * 16 + jj;
            float* obase = (c < HC) ? (xsrc + c) : (xdst + (c - HC));
            #pragma unroll
            for (int r = 0; r < 4; ++r)
                obase[(n0 + hi4 * 4 + r) * HC] = acc[t][r];
        }
    }
}

// ---------------- node GEMM (bf16 inputs): MFMA ----------------
__global__ __launch_bounds__(256) void node_gemm_mfma_k(const unsigned short* __restrict__ x,
                                                        const unsigned short* __restrict__ Wsrc,
                                                        const unsigned short* __restrict__ Wdst,
                                                        const int* __restrict__ flag,
                                                        float* __restrict__ xsrc,
                                                        float* __restrict__ xdst) {
    if (flag[0] != 0) return;        // fp32 inputs: node_gemm_f32s_k handles it
    const int tid = threadIdx.x;
    const int l   = tid & 63;
    const int w   = tid >> 6;
    const int jj  = l & 15;
    const int hi  = l >> 4;
    const int cbase = w * 64;

    bf16x8 bfrag[8][4];
    #pragma unroll
    for (int ks = 0; ks < 8; ++ks)
        #pragma unroll
        for (int t = 0; t < 4; ++t) {
            const int c = cbase + t * 16 + jj;
            const unsigned short* Wp = (c < HC) ? (Wsrc + c) : (Wdst + (c - HC));
            union { unsigned short u[8]; bf16x8 v; } bu;
            #pragma unroll
            for (int i = 0; i < 8; ++i)
                bu.u[i] = Wp[(ks * 32 + hi * 8 + i) * HC];
            bfrag[ks][t] = bu.v;
        }

    for (int nt = blockIdx.x; nt < NTILES; nt += gridDim.x) {
        const long n0 = (long)nt * 16;
        const unsigned short* xr = x + (n0 + jj) * IN_CH + hi * 8;
        bf16x8 afrag[8];
        #pragma unroll
        for (int ks = 0; ks < 8; ++ks)
            afrag[ks] = *(const bf16x8*)(xr + ks * 32);

        f32x4 acc[4];
        #pragma unroll
        for (int t = 0; t < 4; ++t) acc[t] = (f32x4){0.f, 0.f, 0.f, 0.f};
        #pragma unroll
        for (int ks = 0; ks < 8; ++ks)
            #pragma unroll
            for (int t = 0; t < 4; ++t)
                acc[t] = __builtin_amdgcn_mfma_f32_16x16x32_bf16(afrag[ks], bfrag[ks][t], acc[t], 0, 0, 0);

        #pragma unroll
        for (int t = 0; t < 4; ++t) {
            const int c = cbase + t * 16 + jj;
            float* obase = (c < HC) ? (xsrc + c) : (xdst + (c - HC));
            #pragma unroll
            for (int r = 0; r < 4; ++r)
                obase[(n0 + hi * 4 + r) * HC] = acc[t][r];
        }
    }
}

// ---------------- FUSED edge-alpha + aggregation + normalization ----------------
// One wave per dst node (grid-stride, 2048 persistent blocks — R7's proven shape).
// NO LDS staging / NO per-tile barrier: per-lane direct epack loads (one 128B line)
// let the compiler overlap next-tile gathers with current-tile compute.
// Normalization folded in: eaV stored to anorm in-loop, rescaled post-loop by inv[h]
// (wave owns its CSR range exclusively; re-reads its own L2-hot stores).
__global__ __launch_bounds__(256) void fused_edge_agg_k(const int* __restrict__ row_ptr,
                                                        const int2* __restrict__ epack,
                                                        const void* __restrict__ eattr,
                                                        const void* __restrict__ dw,
                                                        const void* __restrict__ Wedge,
                                                        const void* __restrict__ att,
                                                        const void* __restrict__ sscale,
                                                        const int* __restrict__ flag,
                                                        const float* __restrict__ xsrc,
                                                        const float* __restrict__ xdst,
                                                        float* __restrict__ anorm,
                                                        float* __restrict__ araw_out,
                                                        float* __restrict__ out) {
    const bool f32 = (flag[0] != 0);

    const int tid = threadIdx.x;
    const int l   = tid & 63;
    const int wid = tid >> 6;
    const int jj  = l & 15;     // col-within-tile / A-edge index
    const int hi  = l >> 4;     // lane quarter-group

    // B fragments: W_edge[32][128], loaded once per persistent block
    bf16x8 bfrag[8];
    #pragma unroll
    for (int t = 0; t < 8; ++t) {
        union { unsigned short u[8]; bf16x8 v; } bu;
        #pragma unroll
        for (int i = 0; i < 8; ++i) {
            const int k = hi * 8 + i;
            const int col = t * 16 + jj;
            if (f32) bu.u[i] = f2bf(((const float*)Wedge)[k * HC + col]);
            else     bu.u[i] = ((const unsigned short*)Wedge)[k * HC + col];
        }
        bfrag[t] = bu.v;
    }
    float attv[8];
    #pragma unroll
    for (int t = 0; t < 8; ++t) attv[t] = ldf(att, t * 16 + jj, f32);
    float ss4[4];
    #pragma unroll
    for (int h2 = 0; h2 < 4; ++h2) ss4[h2] = ldf(sscale, h2, f32);

    const int nstride = gridDim.x * 4;
    for (int n = blockIdx.x * 4 + wid; n < N_NODES; n += nstride) {
        const int p0 = row_ptr[n];
        const int p1 = row_ptr[n + 1];
        if (p0 >= p1) {                         // empty node: out = 0
            #pragma unroll
            for (int t = 0; t < 2; ++t)
                out[(long)n * HC + jj + 16 * (hi * 2 + t)] = 0.0f;
            continue;
        }

        float xdv[8];
        #pragma unroll
        for (int t = 0; t < 8; ++t) xdv[t] = xdst[(long)n * HC + jj + t * 16];

        float ax[8] = {0,0,0,0,0,0,0,0};
        float sal[4] = {0,0,0,0};

        for (int base = p0; base < p1; base += 16) {
            // per-lane direct CSR loads (one 128B line per tile, L1-broadcast)
            int2 pk[4];
            #pragma unroll
            for (int r = 0; r < 4; ++r)
                pk[r] = epack[min(base + hi * 4 + r, p1 - 1)];
            const int eidA = epack[min(base + jj, p1 - 1)].x;
            float dwv4[4];
            #pragma unroll
            for (int r = 0; r < 4; ++r) dwv4[r] = ldf(dw, pk[r].x, f32);

            // A fragment: eattr row of edge eidA, k-chunk hi*8..hi*8+8
            bf16x8 afrag;
            if (f32) {
                const float* ar = (const float*)eattr + (long)eidA * EDGE_DIM + hi * 8;
                const float4 q0 = *(const float4*)ar;
                const float4 q1 = *(const float4*)(ar + 4);
                union { unsigned short u[8]; bf16x8 v; } au;
                au.u[0] = f2bf(q0.x); au.u[1] = f2bf(q0.y); au.u[2] = f2bf(q0.z); au.u[3] = f2bf(q0.w);
                au.u[4] = f2bf(q1.x); au.u[5] = f2bf(q1.y); au.u[6] = f2bf(q1.z); au.u[7] = f2bf(q1.w);
                afrag = au.v;
            } else {
                afrag = *(const bf16x8*)((const unsigned short*)eattr + (long)eidA * EDGE_DIM + hi * 8);
            }

            const f32x4 zero = {0.f, 0.f, 0.f, 0.f};
            f32x4 acc[8];
            #pragma unroll
            for (int t = 0; t < 8; ++t)
                acc[t] = __builtin_amdgcn_mfma_f32_16x16x32_bf16(afrag, bfrag[t], zero, 0, 0, 0);

            // gather xsrc rows (kept for aggregation), tanh + att partial sums
            float xsv[4][8];
            float hsum[4][4] = {{0,0,0,0},{0,0,0,0},{0,0,0,0},{0,0,0,0}};
            #pragma unroll
            for (int r = 0; r < 4; ++r) {
                const float* bs = xsrc + (long)pk[r].y * HC + jj;
                #pragma unroll
                for (int t = 0; t < 8; ++t) xsv[r][t] = bs[t * 16];
                #pragma unroll
                for (int t = 0; t < 8; ++t) {
                    const float v = ftanh(acc[t][r] + xsv[r][t] + xdv[t]) * attv[t];
                    hsum[r][t >> 1] += v;
                }
            }

            // reduce over the 16 lanes of the group (all lanes end with full sums)
            #pragma unroll
            for (int r = 0; r < 4; ++r)
                #pragma unroll
                for (int h2 = 0; h2 < 4; ++h2) {
                    float v = hsum[r][h2];
                    v += __shfl_xor(v, 1);
                    v += __shfl_xor(v, 2);
                    v += __shfl_xor(v, 4);
                    v += __shfl_xor(v, 8);
                    hsum[r][h2] = v;
                }

            // ea for all (r, head), masked by tile validity
            float eaV[4][4];
            #pragma unroll
            for (int r = 0; r < 4; ++r) {
                const bool valid = (base + hi * 4 + r) < p1;
                const float lg = flog2(dwv4[r]);
                #pragma unroll
                for (int h2 = 0; h2 < 4; ++h2) {
                    const float d = fexp2(ss4[h2] * lg);
                    eaV[r][h2] = valid ? fexp(hsum[r][h2] * d) : 0.0f;
                }
            }

            // scattered per-edge stores: lane jj <-> (r_sel = jj>>2, head = jj&3)
            {
                const int r_sel = jj >> 2, hh = jj & 3;
                if (base + hi * 4 + r_sel < p1) {
                    float pval = hsum[0][0], eval = eaV[0][0];
                    #pragma unroll
                    for (int r = 0; r < 4; ++r)
                        #pragma unroll
                        for (int h2 = 0; h2 < 4; ++h2)
                            if (jj == r * 4 + h2) { pval = hsum[r][h2]; eval = eaV[r][h2]; }
                    const long e2 = pk[r_sel].x;
                    araw_out[e2 * 4 + hh] = pval;
                    anorm[e2 * 4 + hh]    = eval;   // unnormalized; rescaled below
                }
            }

            // aggregation: ax[c] += ea * xs[c]; sal[h] += ea (group-local 4 edges)
            #pragma unroll
            for (int r = 0; r < 4; ++r) {
                #pragma unroll
                for (int t = 0; t < 8; ++t)
                    ax[t] += eaV[r][t >> 1] * xsv[r][t];
                #pragma unroll
                for (int h2 = 0; h2 < 4; ++h2) sal[h2] += eaV[r][h2];
            }
        }

        // combine the 4 lane-groups (lane bits 4,5)
        #pragma unroll
        for (int t = 0; t < 8; ++t) {
            ax[t] += __shfl_xor(ax[t], 16);
            ax[t] += __shfl_xor(ax[t], 32);
        }
        #pragma unroll
        for (int h2 = 0; h2 < 4; ++h2) {
            sal[h2] += __shfl_xor(sal[h2], 16);
            sal[h2] += __shfl_xor(sal[h2], 32);
        }
        const float inv0 = 1.0f / (sal[0] + 1e-8f);
        const float inv1 = 1.0f / (sal[1] + 1e-8f);
        const float inv2 = 1.0f / (sal[2] + 1e-8f);
        const float inv3 = 1.0f / (sal[3] + 1e-8f);

        // out row: lane writes channels jj + 16*(2hi) and jj + 16*(2hi+1), head = hi
        {
            const float invh = (hi == 0) ? inv0 : (hi == 1) ? inv1 : (hi == 2) ? inv2 : inv3;
            const int t0 = hi * 2, t1 = t0 + 1;
            out[(long)n * HC + jj + 16 * t0] = ax[t0] * invh;
            out[(long)n * HC + jj + 16 * t1] = ax[t1] * invh;
        }

        // normalize this node's anorm entries (own CSR range; own stores re-read)
        const int cnt = (p1 - p0) * 4;
        for (int idx = l; idx < cnt; idx += 64) {
            const int p = p0 + (idx >> 2);
            const int h = idx & 3;
            const float iv = (h == 0) ? inv0 : (h == 1) ? inv1 : (h == 2) ? inv2 : inv3;
            const long e = epack[p].x;
            anorm[e * 4 + h] *= iv;
        }
    }
}

extern "C" void kernel_launch(void* const* d_in, const int* in_sizes, int n_in,
                              void* d_out, int out_size, void* d_ws, size_t ws_size,
                              hipStream_t stream) {
    const void* x      = d_in[0];
    const int*  ei     = (const int*)d_in[1];
    const void* eattr  = d_in[2];
    const void* dw     = d_in[3];
    const void* Wsrc   = d_in[4];
    const void* Wdst   = d_in[5];
    const void* Wedge  = d_in[6];
    const void* att    = d_in[7];
    const void* sscale = d_in[8];

    float* out   = (float*)d_out;                   // reference output dtype: float32
    float* anorm = out + (long)N_NODES * HC;
    float* araw  = anorm + (long)N_EDGES * NH;

    float* ws      = (float*)d_ws;
    int*   flag    = (int*)d_ws;                    // 64-float pad
    float* xsrc    = ws + 64;                       // N*128
    float* xdst    = xsrc + (long)N_NODES * HC;     // N*128
    float* unused0 = xdst + (long)N_NODES * HC;     // E*4 (kept for layout stability)
    float* unused1 = unused0 + (long)N_EDGES * NH;  // N*4
    int*   deg     = (int*)(unused1 + (long)N_NODES * NH);   // N
    int*   row_ptr = deg + N_NODES;                 // N+1
    int*   cursor  = row_ptr + N_NODES + 1;         // N
    int*   pad0    = cursor + N_NODES;              // 1 int pad -> 8B alignment
    int2*  epack   = (int2*)(pad0 + 1);             // E int2
    (void)unused0; (void)unused1;

    detect_k<<<1, 256, 0, stream>>>((const unsigned short*)x, ei, flag);
    zero_deg_k<<<(N_NODES + 255) / 256, 256, 0, stream>>>(deg);
    hist_k<<<(N_EDGES + 255) / 256, 256, 0, stream>>>(ei, flag, deg);
    scan1_k<<<SCAN_BLKS, 256, 0, stream>>>(deg, row_ptr);
    scan2_k<<<1, 256, 0, stream>>>(row_ptr);
    scan3_k<<<SCAN_BLKS, 256, 0, stream>>>(row_ptr, cursor);
    scatter_k<<<(N_EDGES + 255) / 256, 256, 0, stream>>>(ei, flag, cursor, epack);
    w_split_k<<<256, 256, 0, stream>>>((const float*)Wsrc, (const float*)Wdst, flag);
    node_gemm_f32s_k<<<512, 512, 0, stream>>>((const float*)x, flag, xsrc, xdst);
    node_gemm_mfma_k<<<1024, 256, 0, stream>>>((const unsigned short*)x,
                                               (const unsigned short*)Wsrc,
                                               (const unsigned short*)Wdst,
                                               flag, xsrc, xdst);
    fused_edge_agg_k<<<2048, 256, 0, stream>>>(row_ptr, epack, eattr, dw, Wedge,
                                               att, sscale, flag, xsrc, xdst,
                                               anorm, araw, out);
}